// Round 1
// baseline (183.213 us; speedup 1.0000x reference)
//
#include <hip/hip_runtime.h>

#define NN 8192      // nodes (2 * batch)
#define NEDGE 524288 // total ragged neighbors
#define EMB 128
#define HID 256

__device__ __forceinline__ void fma4(float4& a, float s, const float4& w) {
    a.x = fmaf(s, w.x, a.x);
    a.y = fmaf(s, w.y, a.y);
    a.z = fmaf(s, w.z, a.z);
    a.w = fmaf(s, w.w, a.w);
}

// ---------------------------------------------------------------------------
// K1: ragged segment-mean aggregation.
// One block per node. 8 groups of 32 lanes; each group walks edges with
// stride 8; each lane owns 4 columns (float4). Reduce groups via LDS.
// ---------------------------------------------------------------------------
__global__ __launch_bounds__(256) void k_aggregate(
    const int* __restrict__ nbr_ent,
    const int* __restrict__ nbr_rel,
    const int* __restrict__ offsets,
    const float* __restrict__ ent_emb,
    const float* __restrict__ rel_emb,
    float* __restrict__ neighbor)   // [NN][256] = [ne_mean | nr_mean]
{
    const int node  = blockIdx.x;
    const int start = offsets[node];
    const int end   = (node + 1 < NN) ? offsets[node + 1] : NEDGE;
    const int cnt   = end - start;

    const int g    = threadIdx.x >> 5;   // 0..7
    const int lane = threadIdx.x & 31;   // 0..31
    const int c    = lane * 4;           // column base

    float4 ae = make_float4(0.f, 0.f, 0.f, 0.f);
    float4 ar = make_float4(0.f, 0.f, 0.f, 0.f);

    for (int e = start + g; e < end; e += 8) {
        const int ie = nbr_ent[e];
        const int ir = nbr_rel[e];
        const float4 ve = *(const float4*)(ent_emb + (size_t)ie * EMB + c);
        const float4 vr = *(const float4*)(rel_emb + (size_t)ir * EMB + c);
        ae.x += ve.x; ae.y += ve.y; ae.z += ve.z; ae.w += ve.w;
        ar.x += vr.x; ar.y += vr.y; ar.z += vr.z; ar.w += vr.w;
    }

    __shared__ float se[8][32][4];
    __shared__ float sr[8][32][4];
    se[g][lane][0] = ae.x; se[g][lane][1] = ae.y;
    se[g][lane][2] = ae.z; se[g][lane][3] = ae.w;
    sr[g][lane][0] = ar.x; sr[g][lane][1] = ar.y;
    sr[g][lane][2] = ar.z; sr[g][lane][3] = ar.w;
    __syncthreads();

    if (threadIdx.x < 32) {
        const int l = threadIdx.x;
        float4 te = make_float4(0.f, 0.f, 0.f, 0.f);
        float4 tr = make_float4(0.f, 0.f, 0.f, 0.f);
        #pragma unroll
        for (int o = 0; o < 8; ++o) {
            te.x += se[o][l][0]; te.y += se[o][l][1];
            te.z += se[o][l][2]; te.w += se[o][l][3];
            tr.x += sr[o][l][0]; tr.y += sr[o][l][1];
            tr.z += sr[o][l][2]; tr.w += sr[o][l][3];
        }
        const float inv = 1.0f / (float)(cnt > 1 ? cnt : 1);
        te.x *= inv; te.y *= inv; te.z *= inv; te.w *= inv;
        tr.x *= inv; tr.y *= inv; tr.z *= inv; tr.w *= inv;
        float* dst = neighbor + (size_t)node * 256;
        *(float4*)(dst + l * 4)       = te;
        *(float4*)(dst + 128 + l * 4) = tr;
    }
}

// ---------------------------------------------------------------------------
// Weight prep: transpose to [k][j] layout for coalesced streaming in GEMMs.
// ---------------------------------------------------------------------------
__global__ void k_prep_w1(const float* __restrict__ Wt,
                          const float* __restrict__ Wn,
                          const float* __restrict__ bt,
                          const float* __restrict__ bn,
                          float* __restrict__ Wcat,    // [384][256]
                          float* __restrict__ bias1)   // [256]
{
    const int k = blockIdx.x;   // 0..383
    const int j = threadIdx.x;  // 0..255
    const float v = (k < EMB) ? Wt[(size_t)j * EMB + k]
                              : Wn[(size_t)j * 256 + (k - EMB)];
    Wcat[(size_t)k * 256 + j] = v;
    if (k == 0) bias1[j] = bt[j] + bn[j];
}

__global__ void k_prep_w2(const float* __restrict__ Wr,
                          float* __restrict__ Wcat2)   // [512][256]
{
    const int k = blockIdx.x;   // 0..511
    const int j = threadIdx.x;  // 0..255
    Wcat2[(size_t)k * 256 + j] = Wr[(size_t)j * 512 + k];
}

// ---------------------------------------------------------------------------
// K2: h = relu(W_t @ xe + W_n @ [ne_mean|nr_mean] + b_t + b_n)   [NN][256]
// Wave handles 4 nodes x 256 cols (4 cols/lane, 16 f32 accumulators).
// Block = 4 waves = 16 nodes. Weights streamed coalesced from Wcat[k][j].
// ---------------------------------------------------------------------------
__global__ __launch_bounds__(256) void k_node_mlp(
    const int* __restrict__ entities,
    const float* __restrict__ ent_emb,
    const float* __restrict__ neighbor,
    const float* __restrict__ Wcat,    // [384][256]
    const float* __restrict__ bias1,   // [256]
    float* __restrict__ h)             // [NN][256]
{
    const int wave = threadIdx.x >> 6;
    const int lane = threadIdx.x & 63;
    const int n0   = blockIdx.x * 16 + wave * 4;
    const int col  = lane * 4;

    const float4 b = *(const float4*)(bias1 + col);
    float4 a0 = b, a1 = b, a2 = b, a3 = b;

    const float* x0 = ent_emb + (size_t)entities[n0 + 0] * EMB;
    const float* x1 = ent_emb + (size_t)entities[n0 + 1] * EMB;
    const float* x2 = ent_emb + (size_t)entities[n0 + 2] * EMB;
    const float* x3 = ent_emb + (size_t)entities[n0 + 3] * EMB;
    const float* w  = Wcat + col;

    #pragma unroll 4
    for (int k = 0; k < EMB; ++k) {
        const float4 wv = *(const float4*)(w + (size_t)k * 256);
        fma4(a0, x0[k], wv);
        fma4(a1, x1[k], wv);
        fma4(a2, x2[k], wv);
        fma4(a3, x3[k], wv);
    }

    const float* y0 = neighbor + (size_t)(n0 + 0) * 256;
    const float* y1 = neighbor + (size_t)(n0 + 1) * 256;
    const float* y2 = neighbor + (size_t)(n0 + 2) * 256;
    const float* y3 = neighbor + (size_t)(n0 + 3) * 256;

    #pragma unroll 4
    for (int k = 0; k < 256; ++k) {
        const float4 wv = *(const float4*)(w + (size_t)(EMB + k) * 256);
        fma4(a0, y0[k], wv);
        fma4(a1, y1[k], wv);
        fma4(a2, y2[k], wv);
        fma4(a3, y3[k], wv);
    }

    float4 accs[4] = {a0, a1, a2, a3};
    #pragma unroll
    for (int n = 0; n < 4; ++n) {
        float4 a = accs[n];
        a.x = fmaxf(a.x, 0.f); a.y = fmaxf(a.y, 0.f);
        a.z = fmaxf(a.z, 0.f); a.w = fmaxf(a.w, 0.f);
        *(float4*)(h + (size_t)(n0 + n) * 256 + col) = a;
    }
}

// ---------------------------------------------------------------------------
// K3: pair = relu(node @ W_r^T + b_r), node = h viewed as [NN/2][512].
// Same wave structure: 4 pairs x 256 cols per wave, k = 512.
// ---------------------------------------------------------------------------
__global__ __launch_bounds__(256) void k_pair_mlp(
    const float* __restrict__ h,       // [NN/2][512]
    const float* __restrict__ Wcat2,   // [512][256]
    const float* __restrict__ br,      // [256]
    float* __restrict__ out)           // [NN/2][256]
{
    const int wave = threadIdx.x >> 6;
    const int lane = threadIdx.x & 63;
    const int p0   = blockIdx.x * 16 + wave * 4;
    const int col  = lane * 4;

    const float4 b = *(const float4*)(br + col);
    float4 a0 = b, a1 = b, a2 = b, a3 = b;

    const float* x0 = h + (size_t)(p0 + 0) * 512;
    const float* x1 = h + (size_t)(p0 + 1) * 512;
    const float* x2 = h + (size_t)(p0 + 2) * 512;
    const float* x3 = h + (size_t)(p0 + 3) * 512;
    const float* w  = Wcat2 + col;

    #pragma unroll 4
    for (int k = 0; k < 512; ++k) {
        const float4 wv = *(const float4*)(w + (size_t)k * 256);
        fma4(a0, x0[k], wv);
        fma4(a1, x1[k], wv);
        fma4(a2, x2[k], wv);
        fma4(a3, x3[k], wv);
    }

    float4 accs[4] = {a0, a1, a2, a3};
    #pragma unroll
    for (int n = 0; n < 4; ++n) {
        float4 a = accs[n];
        a.x = fmaxf(a.x, 0.f); a.y = fmaxf(a.y, 0.f);
        a.z = fmaxf(a.z, 0.f); a.w = fmaxf(a.w, 0.f);
        *(float4*)(out + (size_t)(p0 + n) * 256 + col) = a;
    }
}

// ---------------------------------------------------------------------------
extern "C" void kernel_launch(void* const* d_in, const int* in_sizes, int n_in,
                              void* d_out, int out_size, void* d_ws, size_t ws_size,
                              hipStream_t stream) {
    const int*   entities = (const int*)d_in[0];
    const int*   nbr_ent  = (const int*)d_in[1];
    const int*   nbr_rel  = (const int*)d_in[2];
    const int*   offsets  = (const int*)d_in[3];
    const float* ent_emb  = (const float*)d_in[4];
    const float* rel_emb  = (const float*)d_in[5];
    const float* W_t      = (const float*)d_in[6];
    const float* b_t      = (const float*)d_in[7];
    const float* W_n      = (const float*)d_in[8];
    const float* b_n      = (const float*)d_in[9];
    const float* W_r      = (const float*)d_in[10];
    const float* b_r      = (const float*)d_in[11];
    float* out = (float*)d_out;

    float* ws       = (float*)d_ws;
    float* neighbor = ws;                        // NN*256
    float* h        = neighbor + (size_t)NN * 256; // NN*256
    float* Wcat1    = h + (size_t)NN * 256;      // 384*256
    float* bias1    = Wcat1 + 384 * 256;         // 256
    float* Wcat2    = bias1 + 256;               // 512*256

    hipLaunchKernelGGL(k_prep_w1, dim3(384), dim3(256), 0, stream,
                       W_t, W_n, b_t, b_n, Wcat1, bias1);
    hipLaunchKernelGGL(k_prep_w2, dim3(512), dim3(256), 0, stream,
                       W_r, Wcat2);
    hipLaunchKernelGGL(k_aggregate, dim3(NN), dim3(256), 0, stream,
                       nbr_ent, nbr_rel, offsets, ent_emb, rel_emb, neighbor);
    hipLaunchKernelGGL(k_node_mlp, dim3(NN / 16), dim3(256), 0, stream,
                       entities, ent_emb, neighbor, Wcat1, bias1, h);
    hipLaunchKernelGGL(k_pair_mlp, dim3(NN / 2 / 16), dim3(256), 0, stream,
                       h, Wcat2, b_r, out);
}

// Round 2
// 105.973 us; speedup vs baseline: 1.7289x; 1.7289x over previous
//
#include <hip/hip_runtime.h>

#define NN 8192      // nodes (2 * batch)
#define NEDGE 524288 // total ragged neighbors
#define EMB 128

typedef __attribute__((ext_vector_type(8))) short bf16x8;
typedef __attribute__((ext_vector_type(4))) float f32x4;

__device__ __forceinline__ ushort f2bf(float f) {
    union { float f; uint u; } v; v.f = f;
    return (ushort)((v.u + 0x7FFF + ((v.u >> 16) & 1)) >> 16);  // RNE
}

// ---------------------------------------------------------------------------
// K1: ragged segment-mean aggregation, fused with self-entity gather.
// One block per node. 8 groups of 32 lanes walk edges stride-8; lane owns 4
// cols (float4 = 16B, 32 lanes cover the 512B row). Index prefetch overlaps
// the dependent idx->gather chain. Writes bf16 X row:
//   Xcat[node] = [ ent_row(128) | ne_mean(128) | nr_mean(128) ]
// ---------------------------------------------------------------------------
__global__ __launch_bounds__(256) void k_aggregate(
    const int* __restrict__ entities,
    const int* __restrict__ nbr_ent,
    const int* __restrict__ nbr_rel,
    const int* __restrict__ offsets,
    const float* __restrict__ ent_emb,
    const float* __restrict__ rel_emb,
    ushort* __restrict__ Xcat)          // [NN][384] bf16
{
    const int node  = blockIdx.x;
    const int start = offsets[node];
    const int end   = (node + 1 < NN) ? offsets[node + 1] : NEDGE;
    const int cnt   = end - start;

    const int g    = threadIdx.x >> 5;   // 0..7
    const int lane = threadIdx.x & 31;   // 0..31
    const int c    = lane * 4;

    float4 ae = make_float4(0.f, 0.f, 0.f, 0.f);
    float4 ar = make_float4(0.f, 0.f, 0.f, 0.f);

    int e = start + g;
    int ie = 0, ir = 0;
    if (e < end) { ie = nbr_ent[e]; ir = nbr_rel[e]; }
    while (e < end) {
        const int en = e + 8;
        int ie2 = 0, ir2 = 0;
        if (en < end) { ie2 = nbr_ent[en]; ir2 = nbr_rel[en]; }  // prefetch
        const float4 ve = *(const float4*)(ent_emb + (size_t)ie * EMB + c);
        const float4 vr = *(const float4*)(rel_emb + (size_t)ir * EMB + c);
        ae.x += ve.x; ae.y += ve.y; ae.z += ve.z; ae.w += ve.w;
        ar.x += vr.x; ar.y += vr.y; ar.z += vr.z; ar.w += vr.w;
        ie = ie2; ir = ir2; e = en;
    }

    __shared__ float se[8][32][4];
    __shared__ float sr[8][32][4];
    se[g][lane][0] = ae.x; se[g][lane][1] = ae.y;
    se[g][lane][2] = ae.z; se[g][lane][3] = ae.w;
    sr[g][lane][0] = ar.x; sr[g][lane][1] = ar.y;
    sr[g][lane][2] = ar.z; sr[g][lane][3] = ar.w;
    __syncthreads();

    ushort* xrow = Xcat + (size_t)node * 384;

    if (threadIdx.x < 32) {
        const int l = threadIdx.x;
        float4 te = make_float4(0.f, 0.f, 0.f, 0.f);
        float4 tr = make_float4(0.f, 0.f, 0.f, 0.f);
        #pragma unroll
        for (int o = 0; o < 8; ++o) {
            te.x += se[o][l][0]; te.y += se[o][l][1];
            te.z += se[o][l][2]; te.w += se[o][l][3];
            tr.x += sr[o][l][0]; tr.y += sr[o][l][1];
            tr.z += sr[o][l][2]; tr.w += sr[o][l][3];
        }
        const float inv = 1.0f / (float)(cnt > 1 ? cnt : 1);
        ushort4 ue, ur;
        ue.x = f2bf(te.x * inv); ue.y = f2bf(te.y * inv);
        ue.z = f2bf(te.z * inv); ue.w = f2bf(te.w * inv);
        ur.x = f2bf(tr.x * inv); ur.y = f2bf(tr.y * inv);
        ur.z = f2bf(tr.z * inv); ur.w = f2bf(tr.w * inv);
        *(ushort4*)(xrow + 128 + l * 4) = ue;
        *(ushort4*)(xrow + 256 + l * 4) = ur;
    } else if (threadIdx.x < 64) {
        const int l  = threadIdx.x - 32;
        const int c2 = l * 4;
        const int ent = entities[node];
        const float4 v = *(const float4*)(ent_emb + (size_t)ent * EMB + c2);
        ushort4 u;
        u.x = f2bf(v.x); u.y = f2bf(v.y); u.z = f2bf(v.z); u.w = f2bf(v.w);
        *(ushort4*)(xrow + c2) = u;
    }
}

// ---------------------------------------------------------------------------
// Weight prep: convert to bf16, keep native [n][k] layout (== B^T row-major,
// exactly what the MFMA B-fragment wants). Wb1 = [W_t | W_n] along k.
// ---------------------------------------------------------------------------
__global__ __launch_bounds__(512) void k_prep(
    const float* __restrict__ Wt,   // [256][128]
    const float* __restrict__ Wn,   // [256][256]
    const float* __restrict__ bt,
    const float* __restrict__ bn,
    const float* __restrict__ Wr,   // [256][512]
    ushort* __restrict__ Wb1,       // [256][384] bf16
    float* __restrict__ bias1,      // [256]
    ushort* __restrict__ Wb2)       // [256][512] bf16
{
    const int j = blockIdx.x;    // 0..255
    const int t = threadIdx.x;   // 0..511
    if (t < 384) {
        const float v = (t < 128) ? Wt[(size_t)j * 128 + t]
                                  : Wn[(size_t)j * 256 + (t - 128)];
        Wb1[(size_t)j * 384 + t] = f2bf(v);
    } else if (t == 384) {
        bias1[j] = bt[j] + bn[j];
    }
    Wb2[(size_t)j * 512 + t] = f2bf(Wr[(size_t)j * 512 + t]);
}

// ---------------------------------------------------------------------------
// K2: h = relu(Xcat @ Wb1^T + bias1), bf16 MFMA 16x16x32, f32 accum.
// Wave tile 16(M) x 64(N), block = 4 waves stacked in M -> 64x64 tile.
// A frag: lane (m=l&15, k-octet=l>>4) -> 16B contiguous from [m][k] row-major.
// B frag: lane (n=l&15, k-octet=l>>4) -> 16B contiguous from [n][k] layout.
// C/D: col=l&15, row=(l>>4)*4+reg  [guide-verified m89/m91].
// Output h bf16 [NN][256]  (== pair-GEMM A matrix [NN/2][512]).
// ---------------------------------------------------------------------------
__global__ __launch_bounds__(256) void k_gemm1(
    const ushort* __restrict__ A,     // [NN][384] bf16
    const ushort* __restrict__ B,     // [256][384] bf16
    const float* __restrict__ bias,   // [256]
    ushort* __restrict__ H)           // [NN][256] bf16
{
    const int wave = threadIdx.x >> 6;
    const int lane = threadIdx.x & 63;
    const int m0 = blockIdx.x * 64 + wave * 16;
    const int n0 = blockIdx.y * 64;
    const int lm = lane & 15;
    const int lk = (lane >> 4) * 8;

    const ushort* Ap = A + (size_t)(m0 + lm) * 384 + lk;
    const ushort* Bp0 = B + (size_t)(n0 +  0 + lm) * 384 + lk;
    const ushort* Bp1 = B + (size_t)(n0 + 16 + lm) * 384 + lk;
    const ushort* Bp2 = B + (size_t)(n0 + 32 + lm) * 384 + lk;
    const ushort* Bp3 = B + (size_t)(n0 + 48 + lm) * 384 + lk;

    f32x4 acc0 = {0.f, 0.f, 0.f, 0.f};
    f32x4 acc1 = {0.f, 0.f, 0.f, 0.f};
    f32x4 acc2 = {0.f, 0.f, 0.f, 0.f};
    f32x4 acc3 = {0.f, 0.f, 0.f, 0.f};

    #pragma unroll
    for (int kb = 0; kb < 12; ++kb) {
        const bf16x8 a  = *(const bf16x8*)(Ap  + kb * 32);
        const bf16x8 b0 = *(const bf16x8*)(Bp0 + kb * 32);
        const bf16x8 b1 = *(const bf16x8*)(Bp1 + kb * 32);
        const bf16x8 b2 = *(const bf16x8*)(Bp2 + kb * 32);
        const bf16x8 b3 = *(const bf16x8*)(Bp3 + kb * 32);
        acc0 = __builtin_amdgcn_mfma_f32_16x16x32_bf16(a, b0, acc0, 0, 0, 0);
        acc1 = __builtin_amdgcn_mfma_f32_16x16x32_bf16(a, b1, acc1, 0, 0, 0);
        acc2 = __builtin_amdgcn_mfma_f32_16x16x32_bf16(a, b2, acc2, 0, 0, 0);
        acc3 = __builtin_amdgcn_mfma_f32_16x16x32_bf16(a, b3, acc3, 0, 0, 0);
    }

    const int r0 = (lane >> 4) * 4;
    f32x4 accs[4] = {acc0, acc1, acc2, acc3};
    #pragma unroll
    for (int ni = 0; ni < 4; ++ni) {
        const int col = n0 + ni * 16 + lm;
        const float bv = bias[col];
        #pragma unroll
        for (int j = 0; j < 4; ++j) {
            const int row = m0 + r0 + j;
            const float v = fmaxf(accs[ni][j] + bv, 0.f);
            H[(size_t)row * 256 + col] = f2bf(v);
        }
    }
}

// ---------------------------------------------------------------------------
// K3: pair = relu(H2 @ Wb2^T + b_r), H2 = H viewed [NN/2][512]. Same scheme.
// ---------------------------------------------------------------------------
__global__ __launch_bounds__(256) void k_gemm2(
    const ushort* __restrict__ A,     // [NN/2][512] bf16
    const ushort* __restrict__ B,     // [256][512] bf16
    const float* __restrict__ bias,   // [256]
    float* __restrict__ out)          // [NN/2][256] f32
{
    const int wave = threadIdx.x >> 6;
    const int lane = threadIdx.x & 63;
    const int m0 = blockIdx.x * 64 + wave * 16;
    const int n0 = blockIdx.y * 64;
    const int lm = lane & 15;
    const int lk = (lane >> 4) * 8;

    const ushort* Ap = A + (size_t)(m0 + lm) * 512 + lk;
    const ushort* Bp0 = B + (size_t)(n0 +  0 + lm) * 512 + lk;
    const ushort* Bp1 = B + (size_t)(n0 + 16 + lm) * 512 + lk;
    const ushort* Bp2 = B + (size_t)(n0 + 32 + lm) * 512 + lk;
    const ushort* Bp3 = B + (size_t)(n0 + 48 + lm) * 512 + lk;

    f32x4 acc0 = {0.f, 0.f, 0.f, 0.f};
    f32x4 acc1 = {0.f, 0.f, 0.f, 0.f};
    f32x4 acc2 = {0.f, 0.f, 0.f, 0.f};
    f32x4 acc3 = {0.f, 0.f, 0.f, 0.f};

    #pragma unroll
    for (int kb = 0; kb < 16; ++kb) {
        const bf16x8 a  = *(const bf16x8*)(Ap  + kb * 32);
        const bf16x8 b0 = *(const bf16x8*)(Bp0 + kb * 32);
        const bf16x8 b1 = *(const bf16x8*)(Bp1 + kb * 32);
        const bf16x8 b2 = *(const bf16x8*)(Bp2 + kb * 32);
        const bf16x8 b3 = *(const bf16x8*)(Bp3 + kb * 32);
        acc0 = __builtin_amdgcn_mfma_f32_16x16x32_bf16(a, b0, acc0, 0, 0, 0);
        acc1 = __builtin_amdgcn_mfma_f32_16x16x32_bf16(a, b1, acc1, 0, 0, 0);
        acc2 = __builtin_amdgcn_mfma_f32_16x16x32_bf16(a, b2, acc2, 0, 0, 0);
        acc3 = __builtin_amdgcn_mfma_f32_16x16x32_bf16(a, b3, acc3, 0, 0, 0);
    }

    const int r0 = (lane >> 4) * 4;
    f32x4 accs[4] = {acc0, acc1, acc2, acc3};
    #pragma unroll
    for (int ni = 0; ni < 4; ++ni) {
        const int col = n0 + ni * 16 + lm;
        const float bv = bias[col];
        #pragma unroll
        for (int j = 0; j < 4; ++j) {
            const int row = m0 + r0 + j;
            out[(size_t)row * 256 + col] = fmaxf(accs[ni][j] + bv, 0.f);
        }
    }
}

// ---------------------------------------------------------------------------
extern "C" void kernel_launch(void* const* d_in, const int* in_sizes, int n_in,
                              void* d_out, int out_size, void* d_ws, size_t ws_size,
                              hipStream_t stream) {
    const int*   entities = (const int*)d_in[0];
    const int*   nbr_ent  = (const int*)d_in[1];
    const int*   nbr_rel  = (const int*)d_in[2];
    const int*   offsets  = (const int*)d_in[3];
    const float* ent_emb  = (const float*)d_in[4];
    const float* rel_emb  = (const float*)d_in[5];
    const float* W_t      = (const float*)d_in[6];
    const float* b_t      = (const float*)d_in[7];
    const float* W_n      = (const float*)d_in[8];
    const float* b_n      = (const float*)d_in[9];
    const float* W_r      = (const float*)d_in[10];
    const float* b_r      = (const float*)d_in[11];
    float* out = (float*)d_out;

    char* ws = (char*)d_ws;
    ushort* Xcat  = (ushort*)(ws);                       // NN*384*2  = 6291456 B
    ushort* H     = (ushort*)(ws + 6291456);             // NN*256*2  = 4194304 B
    ushort* Wb1   = (ushort*)(ws + 10485760);            // 256*384*2 = 196608 B
    ushort* Wb2   = (ushort*)(ws + 10682368);            // 256*512*2 = 262144 B
    float*  bias1 = (float*)(ws + 10944512);             // 1024 B

    hipLaunchKernelGGL(k_prep, dim3(256), dim3(512), 0, stream,
                       W_t, W_n, b_t, b_n, W_r, Wb1, bias1, Wb2);
    hipLaunchKernelGGL(k_aggregate, dim3(NN), dim3(256), 0, stream,
                       entities, nbr_ent, nbr_rel, offsets, ent_emb, rel_emb, Xcat);
    hipLaunchKernelGGL(k_gemm1, dim3(NN / 64, 4), dim3(256), 0, stream,
                       Xcat, Wb1, bias1, H);
    hipLaunchKernelGGL(k_gemm2, dim3(NN / 2 / 64, 4), dim3(256), 0, stream,
                       H, Wb2, b_r, out);
}